// Round 9
// baseline (816.131 us; speedup 1.0000x reference)
//
#include <hip/hip_runtime.h>
#include <cstdint>

#define NN 100000
#define EE 1600000
#define GG 64
#define FIN 128
#define HC 256      // H*C for layer 1
#define NC 10

typedef short v8s __attribute__((ext_vector_type(8)));
typedef float v4f __attribute__((ext_vector_type(4)));

static __device__ __forceinline__ float lrelu(float x) { return x > 0.f ? x : 0.2f * x; }
static __device__ __forceinline__ float bf2f(unsigned short b) {
  return __uint_as_float(((unsigned int)b) << 16);
}
static __device__ __forceinline__ unsigned short f2bf(float f) {
  unsigned int u = __float_as_uint(f);
  unsigned int r = (u + 0x7FFFu + ((u >> 16) & 1u)) >> 16;
  return (unsigned short)r;
}
static __device__ __forceinline__ void unpack2(unsigned int u, float& f0, float& f1) {
  f0 = __uint_as_float(u << 16);          // even channel (lo ushort)
  f1 = __uint_as_float(u & 0xFFFF0000u);  // odd channel (hi ushort)
}

// ---------------- prep: edge count | W1 transpose | W2 hi/lo split ----------------
// counts zeroed by hipMemsetAsync before this kernel. Block-uniform branch.
// x->bf16 conversion moved INTO gemm1 (deletes the 77MB prep pass + xb buffer).
__global__ __launch_bounds__(256) void k_prep(const int* __restrict__ ei,
                                              int* __restrict__ counts,
                                              const float* __restrict__ W1,
                                              unsigned short* __restrict__ W1tg,
                                              const float* __restrict__ W2,
                                              unsigned short* __restrict__ W2thi,
                                              unsigned short* __restrict__ W2tlo) {
  const int b = blockIdx.x;
  const int t = threadIdx.x;
  if (b < 6250) {
    const int idx = b * 256 + t;                // 6250*256 == EE exactly
    atomicAdd(&counts[ei[EE + idx]], 1);
  } else if (b < 6506) {
    const int n = b - 6250;                     // 0..255 output column
    if (t < 128) W1tg[n * 128 + t] = f2bf(W1[t * HC + n]);
  } else {
    const int oc = b - 6506;                    // 0..31 output channel
    float wv = W2[t * 32 + oc];
    unsigned short hi = f2bf(wv);
    W2thi[oc * 256 + t] = hi;
    W2tlo[oc * 256 + t] = f2bf(wv - bf2f(hi));
  }
}

// ---------------- GEMM1 (bf16 MFMA, LDS-free, in-register f32->bf16) + scores1 -----
__global__ __launch_bounds__(256) void k_gemm1(const float* __restrict__ x,
                                               const unsigned short* __restrict__ W1tg,
                                               const float* __restrict__ att_src1,
                                               const float* __restrict__ att_dst1,
                                               unsigned short* __restrict__ h1b,
                                               float* __restrict__ as1,
                                               float* __restrict__ ad1) {
  const int t = threadIdx.x;
  const int m0 = blockIdx.x * 64;
  const int n0 = blockIdx.y * 128;
  const int hb = blockIdx.y * 4;       // head base of this column half
  const int lane = t & 63;
  const int wm = t >> 6;               // wave -> m sub-tile
  const int ml = lane & 15;
  const int quad = lane >> 4;
  int row = m0 + wm * 16 + ml; if (row >= NN) row = NN - 1;
  v4f acc[8];
#pragma unroll
  for (int tt = 0; tt < 8; ++tt) acc[tt] = (v4f){0.f, 0.f, 0.f, 0.f};
#pragma unroll
  for (int kk = 0; kk < 4; ++kk) {
    const int k0 = kk * 32 + quad * 8;
    const float4 xa = *(const float4*)(x + (size_t)row * FIN + k0);
    const float4 xc = *(const float4*)(x + (size_t)row * FIN + k0 + 4);
    v8s a;
    a[0] = (short)f2bf(xa.x); a[1] = (short)f2bf(xa.y);
    a[2] = (short)f2bf(xa.z); a[3] = (short)f2bf(xa.w);
    a[4] = (short)f2bf(xc.x); a[5] = (short)f2bf(xc.y);
    a[6] = (short)f2bf(xc.z); a[7] = (short)f2bf(xc.w);
#pragma unroll
    for (int tt = 0; tt < 8; ++tt) {
      v8s b = *(const v8s*)(W1tg + (size_t)(n0 + tt * 16 + ml) * FIN + k0);
      acc[tt] = __builtin_amdgcn_mfma_f32_16x16x32_bf16(a, b, acc[tt], 0, 0, 0);
    }
  }
  // h1b store (C layout: row=quad*4+r, col=tt*16+ml)
#pragma unroll
  for (int tt = 0; tt < 8; ++tt) {
#pragma unroll
    for (int r = 0; r < 4; ++r) {
      int rg = m0 + wm * 16 + quad * 4 + r;
      if (rg < NN) h1b[(size_t)rg * HC + n0 + tt * 16 + ml] = f2bf(acc[tt][r]);
    }
  }
  // fused scores1
  float ps[4][4], pd[4][4];
#pragma unroll
  for (int i = 0; i < 4; ++i)
#pragma unroll
    for (int r = 0; r < 4; ++r) { ps[i][r] = 0.f; pd[i][r] = 0.f; }
#pragma unroll
  for (int i = 0; i < 4; ++i) {
#pragma unroll
    for (int half = 0; half < 2; ++half) {
      const int tt = 2 * i + half;
      const float a_s = att_src1[(hb + i) * 32 + half * 16 + ml];
      const float a_d = att_dst1[(hb + i) * 32 + half * 16 + ml];
#pragma unroll
      for (int r = 0; r < 4; ++r) {
        ps[i][r] += acc[tt][r] * a_s;
        pd[i][r] += acc[tt][r] * a_d;
      }
    }
  }
#pragma unroll
  for (int i = 0; i < 4; ++i) {
#pragma unroll
    for (int r = 0; r < 4; ++r) {
      float s = ps[i][r], d = pd[i][r];
      s += __shfl_xor(s, 1, 64); s += __shfl_xor(s, 2, 64);
      s += __shfl_xor(s, 4, 64); s += __shfl_xor(s, 8, 64);
      d += __shfl_xor(d, 1, 64); d += __shfl_xor(d, 2, 64);
      d += __shfl_xor(d, 4, 64); d += __shfl_xor(d, 8, 64);
      ps[i][r] = s; pd[i][r] = d;
    }
  }
  if (ml == 0) {
#pragma unroll
    for (int r = 0; r < 4; ++r) {
      int rg = m0 + wm * 16 + quad * 4 + r;
      if (rg < NN) {
#pragma unroll
        for (int i = 0; i < 4; ++i) {
          as1[rg * 8 + hb + i] = ps[i][r];
          ad1[rg * 8 + hb + i] = pd[i][r];
        }
      }
    }
  }
}

// ---------------- CSR scan: single block, 1024 threads (replaces scan1/2/3) --------
__global__ __launch_bounds__(1024) void k_scanall(const int* __restrict__ counts,
                                                  int* __restrict__ offs,
                                                  int* __restrict__ cursor,
                                                  int* __restrict__ esrc) {
  __shared__ int ssum[1024];
  const int t = threadIdx.x;
  const int CH = (NN + 1023) / 1024;   // 98
  const int lo = t * CH;
  const int hi = min(lo + CH, NN);
  int s = 0;
  for (int i = lo; i < hi; ++i) s += counts[i];
  ssum[t] = s;
  __syncthreads();
  for (int off = 1; off < 1024; off <<= 1) {
    int v = (t >= off) ? ssum[t - off] : 0;
    __syncthreads();
    ssum[t] += v;
    __syncthreads();
  }
  int run = (t == 0) ? 0 : ssum[t - 1];
  for (int i = lo; i < hi; ++i) {
    int c = counts[i];
    offs[i] = run;
    cursor[i] = run;
    run += c;
  }
  if (t == 0) offs[NN] = EE;
  if (t < 16) esrc[EE + t] = 0;        // zero pad for padded-batch gathers
}

// ---------------- scatter: pure CSR permutation ----------------
__global__ void k_scatter(const int* __restrict__ ei, int* __restrict__ cursor,
                          int* __restrict__ esrc) {
  int e = blockIdx.x * 256 + threadIdx.x;
  if (e < EE) {
    int s = ei[e];
    int d = ei[EE + e];
    int p = atomicAdd(&cursor[d], 1);
    esrc[p] = s;
  }
}

// ---------------- agg1: wave-per-node gather + ELU, then MFMA GEMM2 + scores2 ------
// R3/R8-verified gather structure verbatim; 8 nodes per 512-thread block so the
// wave-0 GEMM2 tail (48 MFMA + W2 reads) amortizes over 8 nodes (M=8 in the
// 16x16 tile, quad<2 guard). NOTE (R6/R7 A/B): per-wave barrier-free GEMM2
// regresses 171 -> 435 us (every wave streams 32KB W2) — keep wave-0 epilogue.
__global__ __launch_bounds__(512) void k_agg1(const unsigned short* __restrict__ h1b,
                                              const float* __restrict__ as1,
                                              const float* __restrict__ ad1,
                                              const int* __restrict__ offs,
                                              const int* __restrict__ esrc,
                                              const float* __restrict__ b1,
                                              const unsigned short* __restrict__ W2thi,
                                              const unsigned short* __restrict__ W2tlo,
                                              const float* __restrict__ att_src2,
                                              const float* __restrict__ att_dst2,
                                              unsigned short* __restrict__ h2b,
                                              float* __restrict__ as2,
                                              float* __restrict__ ad2) {
  __shared__ float wl[8][8][36];                                       // stride 36 floats
  __shared__ __attribute__((aligned(16))) unsigned short o1hi[8][272]; // 544B rows
  __shared__ __attribute__((aligned(16))) unsigned short o1lo[8][272];
  const int t = threadIdx.x;
  const int lane = t & 63;
  const int w = t >> 6;                // 0..7
  const int n0 = blockIdx.x * 8;       // NN = 12500*8 exactly
  const int nu = __builtin_amdgcn_readfirstlane(n0 + w);   // SGPR node id
  const int hl = lane & 31;
  const int half = lane >> 5;
  const int head = lane >> 3;          // head of this lane's 4 channels
  const uint2* __restrict__ h1u2 = (const uint2*)h1b;
  const int start = offs[nu], end = offs[nu + 1];          // s_load
  const float4 dnA = *(const float4*)(ad1 + (size_t)nu * 8);
  const float4 dnB = *(const float4*)(ad1 + (size_t)nu * 8 + 4);
  const float4 dn4 = (lane & 32) ? dnB : dnA;   // weight-phase mapping

  float z, a0, a1, a2, a3;
  {  // self loop
    float w0 = __expf(lrelu(as1[nu * 8 + head] + ad1[nu * 8 + head]));
    uint2 q = h1u2[(size_t)nu * 64 + lane];
    float f0, f1, f2, f3; unpack2(q.x, f0, f1); unpack2(q.y, f2, f3);
    z = w0; a0 = w0 * f0; a1 = w0 * f1; a2 = w0 * f2; a3 = w0 * f3;
  }
  for (int base = start; base < end; base += 32) {
    const int cnt = min(32, end - base);
    // ---- weight phase: lanes 0-31 heads 0-3, lanes 32-63 heads 4-7 ----
    int s = 0;
    if (hl < cnt) s = esrc[base + hl];
    const int hb4 = half << 2;           // 0 or 4
    const float4 av = *(const float4*)(as1 + (size_t)s * 8 + hb4);
    float w0 = __expf(lrelu(av.x + dn4.x));
    float w1 = __expf(lrelu(av.y + dn4.y));
    float w2 = __expf(lrelu(av.z + dn4.z));
    float w3 = __expf(lrelu(av.w + dn4.w));
    const bool act = hl < cnt;
    wl[w][hb4 + 0][hl] = act ? w0 : 0.f;
    wl[w][hb4 + 1][hl] = act ? w1 : 0.f;
    wl[w][hb4 + 2][hl] = act ? w2 : 0.f;
    wl[w][hb4 + 3][hl] = act ? w3 : 0.f;
    // same-wave LDS write->read: compiler inserts lgkmcnt wait
    const int cnt4 = (cnt + 3) & ~3;
    int jb = 0;
    for (; jb + 8 <= cnt4; jb += 8) {
      uint2 q[8];
#pragma unroll
      for (int u = 0; u < 8; ++u) {
        const int sj = esrc[base + jb + u];            // uniform -> s_load
        q[u] = h1u2[(size_t)sj * 64 + lane];
      }
      const float4 wq0 = *(const float4*)&wl[w][head][jb];
      const float4 wq1 = *(const float4*)&wl[w][head][jb + 4];
      z += ((wq0.x + wq0.y) + (wq0.z + wq0.w)) + ((wq1.x + wq1.y) + (wq1.z + wq1.w));
      float f0, f1, f2, f3;
      unpack2(q[0].x, f0, f1); unpack2(q[0].y, f2, f3);
      a0 += wq0.x * f0; a1 += wq0.x * f1; a2 += wq0.x * f2; a3 += wq0.x * f3;
      unpack2(q[1].x, f0, f1); unpack2(q[1].y, f2, f3);
      a0 += wq0.y * f0; a1 += wq0.y * f1; a2 += wq0.y * f2; a3 += wq0.y * f3;
      unpack2(q[2].x, f0, f1); unpack2(q[2].y, f2, f3);
      a0 += wq0.z * f0; a1 += wq0.z * f1; a2 += wq0.z * f2; a3 += wq0.z * f3;
      unpack2(q[3].x, f0, f1); unpack2(q[3].y, f2, f3);
      a0 += wq0.w * f0; a1 += wq0.w * f1; a2 += wq0.w * f2; a3 += wq0.w * f3;
      unpack2(q[4].x, f0, f1); unpack2(q[4].y, f2, f3);
      a0 += wq1.x * f0; a1 += wq1.x * f1; a2 += wq1.x * f2; a3 += wq1.x * f3;
      unpack2(q[5].x, f0, f1); unpack2(q[5].y, f2, f3);
      a0 += wq1.y * f0; a1 += wq1.y * f1; a2 += wq1.y * f2; a3 += wq1.y * f3;
      unpack2(q[6].x, f0, f1); unpack2(q[6].y, f2, f3);
      a0 += wq1.z * f0; a1 += wq1.z * f1; a2 += wq1.z * f2; a3 += wq1.z * f3;
      unpack2(q[7].x, f0, f1); unpack2(q[7].y, f2, f3);
      a0 += wq1.w * f0; a1 += wq1.w * f1; a2 += wq1.w * f2; a3 += wq1.w * f3;
    }
    if (jb < cnt4) {   // 4-edge tail batch
      uint2 q[4];
#pragma unroll
      for (int u = 0; u < 4; ++u) {
        const int sj = esrc[base + jb + u];            // uniform -> s_load
        q[u] = h1u2[(size_t)sj * 64 + lane];
      }
      const float4 wq0 = *(const float4*)&wl[w][head][jb];
      z += (wq0.x + wq0.y) + (wq0.z + wq0.w);
      float f0, f1, f2, f3;
      unpack2(q[0].x, f0, f1); unpack2(q[0].y, f2, f3);
      a0 += wq0.x * f0; a1 += wq0.x * f1; a2 += wq0.x * f2; a3 += wq0.x * f3;
      unpack2(q[1].x, f0, f1); unpack2(q[1].y, f2, f3);
      a0 += wq0.y * f0; a1 += wq0.y * f1; a2 += wq0.y * f2; a3 += wq0.y * f3;
      unpack2(q[2].x, f0, f1); unpack2(q[2].y, f2, f3);
      a0 += wq0.z * f0; a1 += wq0.z * f1; a2 += wq0.z * f2; a3 += wq0.z * f3;
      unpack2(q[3].x, f0, f1); unpack2(q[3].y, f2, f3);
      a0 += wq0.w * f0; a1 += wq0.w * f1; a2 += wq0.w * f2; a3 += wq0.w * f3;
    }
  }
  // out1 = acc/z + b1, ELU; bf16 hi/lo split to LDS (channels 4*lane..+3)
  {
    const float zi = 1.0f / (z + 1e-16f);
    const float4 bb = *(const float4*)(b1 + 4 * lane);
    float v0 = a0 * zi + bb.x;
    float v1 = a1 * zi + bb.y;
    float v2 = a2 * zi + bb.z;
    float v3 = a3 * zi + bb.w;
    v0 = v0 > 0.f ? v0 : (__expf(v0) - 1.0f);
    v1 = v1 > 0.f ? v1 : (__expf(v1) - 1.0f);
    v2 = v2 > 0.f ? v2 : (__expf(v2) - 1.0f);
    v3 = v3 > 0.f ? v3 : (__expf(v3) - 1.0f);
    ushort4 hh, ll;
    hh.x = f2bf(v0); hh.y = f2bf(v1); hh.z = f2bf(v2); hh.w = f2bf(v3);
    ll.x = f2bf(v0 - bf2f(hh.x));
    ll.y = f2bf(v1 - bf2f(hh.y));
    ll.z = f2bf(v2 - bf2f(hh.z));
    ll.w = f2bf(v3 - bf2f(hh.w));
    *(ushort4*)&o1hi[w][4 * lane] = hh;
    *(ushort4*)&o1lo[w][4 * lane] = ll;
  }
  __syncthreads();
  if (w == 0) {
    // GEMM2: M=8 nodes x N=32 x K=256 on the matrix pipe (hi/lo split ~ f32)
    const int ml = lane & 15;
    const int quad = lane >> 4;
    const int mr = ml & 7;               // rows 8..15 duplicate rows 0..7 (ignored)
    v4f acc[2];
    acc[0] = (v4f){0.f, 0.f, 0.f, 0.f};
    acc[1] = (v4f){0.f, 0.f, 0.f, 0.f};
#pragma unroll
    for (int kk = 0; kk < 8; ++kk) {
      const int k0 = kk * 32 + quad * 8;
      v8s ah = *(const v8s*)&o1hi[mr][k0];
      v8s al = *(const v8s*)&o1lo[mr][k0];
#pragma unroll
      for (int tt = 0; tt < 2; ++tt) {
        v8s bh = *(const v8s*)(W2thi + (size_t)(tt * 16 + ml) * 256 + k0);
        v8s bl = *(const v8s*)(W2tlo + (size_t)(tt * 16 + ml) * 256 + k0);
        acc[tt] = __builtin_amdgcn_mfma_f32_16x16x32_bf16(ah, bh, acc[tt], 0, 0, 0);
        acc[tt] = __builtin_amdgcn_mfma_f32_16x16x32_bf16(al, bh, acc[tt], 0, 0, 0);
        acc[tt] = __builtin_amdgcn_mfma_f32_16x16x32_bf16(ah, bl, acc[tt], 0, 0, 0);
      }
    }
    // valid C rows 0..7 = quad 0 (r=0..3) and quad 1 (r=4..7)
    if (quad < 2) {
      const float s0 = att_src2[ml], s1 = att_src2[16 + ml];
      const float d0 = att_dst2[ml], d1 = att_dst2[16 + ml];
#pragma unroll
      for (int r = 0; r < 4; ++r) {
        const int nn = n0 + quad * 4 + r;
        const float h0 = acc[0][r], h1v = acc[1][r];
        h2b[(size_t)nn * 32 + ml] = f2bf(h0);
        h2b[(size_t)nn * 32 + 16 + ml] = f2bf(h1v);
        float ps = h0 * s0 + h1v * s1;
        float pd = h0 * d0 + h1v * d1;
        ps += __shfl_xor(ps, 1, 64); ps += __shfl_xor(ps, 2, 64);
        ps += __shfl_xor(ps, 4, 64); ps += __shfl_xor(ps, 8, 64);
        pd += __shfl_xor(pd, 1, 64); pd += __shfl_xor(pd, 2, 64);
        pd += __shfl_xor(pd, 4, 64); pd += __shfl_xor(pd, 8, 64);
        if (ml == 0) { as2[nn] = ps; ad2[nn] = pd; }
      }
    }
  }
}

// ---------------- agg2: wave-per-node, LDS (src,weight) chunk, 8 edges in flight ---
// R8-verified. Slot group handles edges 8j+slot and 8j+4+slot; OOB swl = (0,0.0).
__global__ __launch_bounds__(256) void k_agg2(const unsigned short* __restrict__ h2b,
                                              const float* __restrict__ as2,
                                              const float* __restrict__ ad2,
                                              const int* __restrict__ offs,
                                              const int* __restrict__ esrc,
                                              const float* __restrict__ b2,
                                              float* __restrict__ h3) {
  __shared__ int2 swl[4][64];   // per-wave (src, weight-bits)
  const int t = threadIdx.x;
  const int lane = t & 63;
  const int wv = t >> 6;
  const int n = __builtin_amdgcn_readfirstlane(blockIdx.x * 4 + wv);  // NN = 25000*4
  const int col = lane & 15;
  const int slot = lane >> 4;
  const unsigned int* __restrict__ h2u = (const unsigned int*)h2b;
  const int start = offs[n], end = offs[n + 1];   // s_load
  const float adn = ad2[n];                       // s_load
  float z = 0.f, acc0 = 0.f, acc1 = 0.f;
  if (slot == 0) {   // self loop counted once
    float w0 = __expf(lrelu(as2[n] + adn));
    unsigned int q = h2u[(unsigned)(n * 16 + col)];
    float f0, f1; unpack2(q, f0, f1);
    z = w0; acc0 = w0 * f0; acc1 = w0 * f1;
  }
  for (int base = start; base < end; base += 64) {
    const int cnt = min(64, end - base);
    int s = 0; float wgt = 0.f;
    if (lane < cnt) {
      s = esrc[base + lane];
      wgt = __expf(lrelu(as2[s] + adn));
    }
    swl[wv][lane] = make_int2(s, __float_as_int(wgt));
    // same-wave LDS write->read: compiler inserts lgkmcnt wait
    const int nit = (cnt + 7) >> 3;
#pragma unroll 2
    for (int j = 0; j < nit; ++j) {
      const int2 p0 = swl[wv][8 * j + slot];
      const int2 p1 = swl[wv][8 * j + 4 + slot];
      const unsigned int q0 = h2u[(unsigned)(p0.x * 16 + col)];
      const unsigned int q1 = h2u[(unsigned)(p1.x * 16 + col)];
      const float wj0 = __int_as_float(p0.y);
      const float wj1 = __int_as_float(p1.y);
      float f0, f1, g0, g1;
      unpack2(q0, f0, f1); unpack2(q1, g0, g1);
      z += wj0 + wj1;
      acc0 += wj0 * f0; acc0 += wj1 * g0;
      acc1 += wj0 * f1; acc1 += wj1 * g1;
    }
  }
  // combine the 4 slot groups
  acc0 += __shfl_xor(acc0, 16, 64); acc0 += __shfl_xor(acc0, 32, 64);
  acc1 += __shfl_xor(acc1, 16, 64); acc1 += __shfl_xor(acc1, 32, 64);
  z    += __shfl_xor(z, 16, 64);    z    += __shfl_xor(z, 32, 64);
  if (slot == 0) {
    const float zi = 1.0f / (z + 1e-16f);
    float2 bb = *(const float2*)(b2 + 2 * col);
    float2 o;
    o.x = acc0 * zi + bb.x;
    o.y = acc1 * zi + bb.y;
    *(float2*)(h3 + (size_t)n * 32 + 2 * col) = o;
  }
}

// ---------------- pool + final linear (fused) ----------------
__global__ __launch_bounds__(256) void k_poolfin(const float* __restrict__ h3,
                                                 const int* __restrict__ batch,
                                                 const float* __restrict__ Wlin,
                                                 const float* __restrict__ blin,
                                                 float* __restrict__ out) {
  __shared__ int bounds[2];
  __shared__ float red[8][33];
  __shared__ float mean[32];
  const int g = blockIdx.x;
  const int t = threadIdx.x;
  if (t < 2) {
    int target = g + t;
    int lo = 0, hi = NN;
    while (lo < hi) { int mid = (lo + hi) >> 1; if (batch[mid] < target) lo = mid + 1; else hi = mid; }
    bounds[t] = lo;
  }
  __syncthreads();
  const int lo = bounds[0], hi = bounds[1];
  const int rr = t >> 5, c = t & 31;
  float a = 0.f;
  for (int r = lo + rr; r < hi; r += 8) a += h3[(size_t)r * 32 + c];
  red[rr][c] = a;
  __syncthreads();
  if (rr == 0) {
    float s = 0.f;
#pragma unroll
    for (int i = 0; i < 8; ++i) s += red[i][c];
    float ct = (float)(hi - lo);
    ct = ct > 1.f ? ct : 1.f;
    mean[c] = s / ct;
  }
  __syncthreads();
  if (t < NC) {
    float acc = 0.f;
#pragma unroll
    for (int cc = 0; cc < 32; ++cc) acc += mean[cc] * Wlin[cc * NC + t];
    out[g * NC + t] = acc + blin[t];
  }
}

extern "C" void kernel_launch(void* const* d_in, const int* in_sizes, int n_in,
                              void* d_out, int out_size, void* d_ws, size_t ws_size,
                              hipStream_t stream) {
  const float* x        = (const float*)d_in[0];
  const int*   ei       = (const int*)d_in[1];
  const int*   batch    = (const int*)d_in[2];
  const float* W1       = (const float*)d_in[3];
  const float* att_src1 = (const float*)d_in[4];
  const float* att_dst1 = (const float*)d_in[5];
  const float* b1       = (const float*)d_in[6];
  const float* W2       = (const float*)d_in[7];
  const float* att_src2 = (const float*)d_in[8];
  const float* att_dst2 = (const float*)d_in[9];
  const float* b2       = (const float*)d_in[10];
  const float* Wlin     = (const float*)d_in[11];
  const float* blin     = (const float*)d_in[12];
  float* out = (float*)d_out;
  char* ws = (char*)d_ws;

  // workspace layout (bytes); peak ~85.3 MB (xb eliminated)
  unsigned short* h1b   = (unsigned short*)(ws + 0);         // 51,200,000
  float* as1    = (float*)(ws + 51200000);                   // 3,200,000
  float* ad1    = (float*)(ws + 54400000);                   // 3,200,000
  int* counts   = (int*)(ws + 57600000);                     // 400,000
  int* offs     = (int*)(ws + 58000000);                     // 400,004 (+pad)
  int* cursor   = (int*)(ws + 58400256);                     // 400,000
  int* esrc     = (int*)(ws + 58800256);                     // 6,400,000 + 64B zero pad
  unsigned short* h2b   = (unsigned short*)(ws + 65200384);  // 6,400,000
  float* as2    = (float*)(ws + 71600384);                   // 400,000
  float* ad2    = (float*)(ws + 72000384);                   // 400,000
  unsigned short* W1tg  = (unsigned short*)(ws + 72400384);  // 65,536
  unsigned short* W2thi = (unsigned short*)(ws + 72465920);  // 16,384
  unsigned short* W2tlo = (unsigned short*)(ws + 72482304);  // 16,384
  float* h3     = (float*)(ws + 72498688);                   // 12,800,000

  hipMemsetAsync(counts, 0, NN * sizeof(int), stream);
  k_prep<<<6538, 256, 0, stream>>>(ei, counts, W1, W1tg, W2, W2thi, W2tlo);

  dim3 g1((NN + 63) / 64, 2);
  k_gemm1<<<g1, 256, 0, stream>>>(x, W1tg, att_src1, att_dst1, h1b, as1, ad1);

  k_scanall<<<1, 1024, 0, stream>>>(counts, offs, cursor, esrc);
  k_scatter<<<(EE + 255) / 256, 256, 0, stream>>>(ei, cursor, esrc);

  k_agg1<<<NN / 8, 512, 0, stream>>>(h1b, as1, ad1, offs, esrc, b1, W2thi, W2tlo,
                                     att_src2, att_dst2, h2b, as2, ad2);

  k_agg2<<<NN / 4, 256, 0, stream>>>(h2b, as2, ad2, offs, esrc, b2, h3);
  k_poolfin<<<GG, 256, 0, stream>>>(h3, batch, Wlin, blin, out);
}

// Round 10
// 581.856 us; speedup vs baseline: 1.4026x; 1.4026x over previous
//
#include <hip/hip_runtime.h>
#include <cstdint>

#define NN 100000
#define EE 1600000
#define GG 64
#define FIN 128
#define HC 256      // H*C for layer 1
#define NC 10

typedef short v8s __attribute__((ext_vector_type(8)));
typedef float v4f __attribute__((ext_vector_type(4)));

static __device__ __forceinline__ float lrelu(float x) { return x > 0.f ? x : 0.2f * x; }
static __device__ __forceinline__ float bf2f(unsigned short b) {
  return __uint_as_float(((unsigned int)b) << 16);
}
static __device__ __forceinline__ unsigned short f2bf(float f) {
  unsigned int u = __float_as_uint(f);
  unsigned int r = (u + 0x7FFFu + ((u >> 16) & 1u)) >> 16;
  return (unsigned short)r;
}
static __device__ __forceinline__ void unpack2(unsigned int u, float& f0, float& f1) {
  f0 = __uint_as_float(u << 16);          // even channel (lo ushort)
  f1 = __uint_as_float(u & 0xFFFF0000u);  // odd channel (hi ushort)
}

// ---------------- prep: edge count | W1 transpose | W2 hi/lo split ----------------
// counts zeroed by hipMemsetAsync before this kernel. Block-uniform branch.
// x->bf16 conversion lives INSIDE gemm1 (deletes the 77MB prep pass + xb buffer).
__global__ __launch_bounds__(256) void k_prep(const int* __restrict__ ei,
                                              int* __restrict__ counts,
                                              const float* __restrict__ W1,
                                              unsigned short* __restrict__ W1tg,
                                              const float* __restrict__ W2,
                                              unsigned short* __restrict__ W2thi,
                                              unsigned short* __restrict__ W2tlo) {
  const int b = blockIdx.x;
  const int t = threadIdx.x;
  if (b < 6250) {
    const int idx = b * 256 + t;                // 6250*256 == EE exactly
    atomicAdd(&counts[ei[EE + idx]], 1);
  } else if (b < 6506) {
    const int n = b - 6250;                     // 0..255 output column
    if (t < 128) W1tg[n * 128 + t] = f2bf(W1[t * HC + n]);
  } else {
    const int oc = b - 6506;                    // 0..31 output channel
    float wv = W2[t * 32 + oc];
    unsigned short hi = f2bf(wv);
    W2thi[oc * 256 + t] = hi;
    W2tlo[oc * 256 + t] = f2bf(wv - bf2f(hi));
  }
}

// ---------------- GEMM1 (bf16 MFMA, LDS-free, in-register f32->bf16) + scores1 -----
__global__ __launch_bounds__(256) void k_gemm1(const float* __restrict__ x,
                                               const unsigned short* __restrict__ W1tg,
                                               const float* __restrict__ att_src1,
                                               const float* __restrict__ att_dst1,
                                               unsigned short* __restrict__ h1b,
                                               float* __restrict__ as1,
                                               float* __restrict__ ad1) {
  const int t = threadIdx.x;
  const int m0 = blockIdx.x * 64;
  const int n0 = blockIdx.y * 128;
  const int hb = blockIdx.y * 4;       // head base of this column half
  const int lane = t & 63;
  const int wm = t >> 6;               // wave -> m sub-tile
  const int ml = lane & 15;
  const int quad = lane >> 4;
  int row = m0 + wm * 16 + ml; if (row >= NN) row = NN - 1;
  v4f acc[8];
#pragma unroll
  for (int tt = 0; tt < 8; ++tt) acc[tt] = (v4f){0.f, 0.f, 0.f, 0.f};
#pragma unroll
  for (int kk = 0; kk < 4; ++kk) {
    const int k0 = kk * 32 + quad * 8;
    const float4 xa = *(const float4*)(x + (size_t)row * FIN + k0);
    const float4 xc = *(const float4*)(x + (size_t)row * FIN + k0 + 4);
    v8s a;
    a[0] = (short)f2bf(xa.x); a[1] = (short)f2bf(xa.y);
    a[2] = (short)f2bf(xa.z); a[3] = (short)f2bf(xa.w);
    a[4] = (short)f2bf(xc.x); a[5] = (short)f2bf(xc.y);
    a[6] = (short)f2bf(xc.z); a[7] = (short)f2bf(xc.w);
#pragma unroll
    for (int tt = 0; tt < 8; ++tt) {
      v8s b = *(const v8s*)(W1tg + (size_t)(n0 + tt * 16 + ml) * FIN + k0);
      acc[tt] = __builtin_amdgcn_mfma_f32_16x16x32_bf16(a, b, acc[tt], 0, 0, 0);
    }
  }
  // h1b store (C layout: row=quad*4+r, col=tt*16+ml)
#pragma unroll
  for (int tt = 0; tt < 8; ++tt) {
#pragma unroll
    for (int r = 0; r < 4; ++r) {
      int rg = m0 + wm * 16 + quad * 4 + r;
      if (rg < NN) h1b[(size_t)rg * HC + n0 + tt * 16 + ml] = f2bf(acc[tt][r]);
    }
  }
  // fused scores1
  float ps[4][4], pd[4][4];
#pragma unroll
  for (int i = 0; i < 4; ++i)
#pragma unroll
    for (int r = 0; r < 4; ++r) { ps[i][r] = 0.f; pd[i][r] = 0.f; }
#pragma unroll
  for (int i = 0; i < 4; ++i) {
#pragma unroll
    for (int half = 0; half < 2; ++half) {
      const int tt = 2 * i + half;
      const float a_s = att_src1[(hb + i) * 32 + half * 16 + ml];
      const float a_d = att_dst1[(hb + i) * 32 + half * 16 + ml];
#pragma unroll
      for (int r = 0; r < 4; ++r) {
        ps[i][r] += acc[tt][r] * a_s;
        pd[i][r] += acc[tt][r] * a_d;
      }
    }
  }
#pragma unroll
  for (int i = 0; i < 4; ++i) {
#pragma unroll
    for (int r = 0; r < 4; ++r) {
      float s = ps[i][r], d = pd[i][r];
      s += __shfl_xor(s, 1, 64); s += __shfl_xor(s, 2, 64);
      s += __shfl_xor(s, 4, 64); s += __shfl_xor(s, 8, 64);
      d += __shfl_xor(d, 1, 64); d += __shfl_xor(d, 2, 64);
      d += __shfl_xor(d, 4, 64); d += __shfl_xor(d, 8, 64);
      ps[i][r] = s; pd[i][r] = d;
    }
  }
  if (ml == 0) {
#pragma unroll
    for (int r = 0; r < 4; ++r) {
      int rg = m0 + wm * 16 + quad * 4 + r;
      if (rg < NN) {
#pragma unroll
        for (int i = 0; i < 4; ++i) {
          as1[rg * 8 + hb + i] = ps[i][r];
          ad1[rg * 8 + hb + i] = pd[i][r];
        }
      }
    }
  }
}

// ---------------- CSR build (R8-verified 3-kernel scan; R9's 1-block scan = 233us) --
__global__ void k_scan1(const int* __restrict__ counts, int* __restrict__ offs,
                        int* __restrict__ bsums) {
  __shared__ int s[256];
  const int t = threadIdx.x;
  const int i = blockIdx.x * 256 + t;
  int v = (i < NN) ? counts[i] : 0;
  s[t] = v;
  __syncthreads();
  for (int off = 1; off < 256; off <<= 1) {
    int tv = (t >= off) ? s[t - off] : 0;
    __syncthreads();
    s[t] += tv;
    __syncthreads();
  }
  if (i < NN) offs[i] = s[t] - v;
  if (t == 255) bsums[blockIdx.x] = s[255];
}

__global__ void k_scan2(int* __restrict__ bsums, int nb) {
  __shared__ int s[512];
  const int t = threadIdx.x;
  int v = (t < nb) ? bsums[t] : 0;
  s[t] = v;
  __syncthreads();
  for (int off = 1; off < 512; off <<= 1) {
    int tv = (t >= off) ? s[t - off] : 0;
    __syncthreads();
    s[t] += tv;
    __syncthreads();
  }
  if (t < nb) bsums[t] = s[t] - v;
}

__global__ void k_scan3(int* __restrict__ offs, const int* __restrict__ bsums,
                        int* __restrict__ cursor, int* __restrict__ esrc) {
  const int i = blockIdx.x * 256 + threadIdx.x;
  if (i < NN) {
    int v = offs[i] + bsums[i >> 8];
    offs[i] = v;
    cursor[i] = v;
  }
  if (i == 0) offs[NN] = EE;
  if (blockIdx.x == 0 && threadIdx.x < 16) esrc[EE + threadIdx.x] = 0;  // pad zero
}

// ---------------- scatter: pure CSR permutation ----------------
__global__ void k_scatter(const int* __restrict__ ei, int* __restrict__ cursor,
                          int* __restrict__ esrc) {
  int e = blockIdx.x * 256 + threadIdx.x;
  if (e < EE) {
    int s = ei[e];
    int d = ei[EE + e];
    int p = atomicAdd(&cursor[d], 1);
    esrc[p] = s;
  }
}

// ---------------- agg1: wave-per-node gather + ELU, then MFMA GEMM2 + scores2 ------
// R3/R8-verified gather structure verbatim; 8 nodes per 512-thread block so the
// wave-0 GEMM2 tail (48 MFMA + W2 reads) amortizes over 8 nodes (M=8 in the
// 16x16 tile, quad<2 guard). NOTE (R6/R7 A/B): per-wave barrier-free GEMM2
// regresses 171 -> 435 us (every wave streams 32KB W2) — keep wave-0 epilogue.
__global__ __launch_bounds__(512) void k_agg1(const unsigned short* __restrict__ h1b,
                                              const float* __restrict__ as1,
                                              const float* __restrict__ ad1,
                                              const int* __restrict__ offs,
                                              const int* __restrict__ esrc,
                                              const float* __restrict__ b1,
                                              const unsigned short* __restrict__ W2thi,
                                              const unsigned short* __restrict__ W2tlo,
                                              const float* __restrict__ att_src2,
                                              const float* __restrict__ att_dst2,
                                              unsigned short* __restrict__ h2b,
                                              float* __restrict__ as2,
                                              float* __restrict__ ad2) {
  __shared__ float wl[8][8][36];                                       // stride 36 floats
  __shared__ __attribute__((aligned(16))) unsigned short o1hi[8][272]; // 544B rows
  __shared__ __attribute__((aligned(16))) unsigned short o1lo[8][272];
  const int t = threadIdx.x;
  const int lane = t & 63;
  const int w = t >> 6;                // 0..7
  const int n0 = blockIdx.x * 8;       // NN = 12500*8 exactly
  const int nu = __builtin_amdgcn_readfirstlane(n0 + w);   // SGPR node id
  const int hl = lane & 31;
  const int half = lane >> 5;
  const int head = lane >> 3;          // head of this lane's 4 channels
  const uint2* __restrict__ h1u2 = (const uint2*)h1b;
  const int start = offs[nu], end = offs[nu + 1];          // s_load
  const float4 dnA = *(const float4*)(ad1 + (size_t)nu * 8);
  const float4 dnB = *(const float4*)(ad1 + (size_t)nu * 8 + 4);
  const float4 dn4 = (lane & 32) ? dnB : dnA;   // weight-phase mapping

  float z, a0, a1, a2, a3;
  {  // self loop
    float w0 = __expf(lrelu(as1[nu * 8 + head] + ad1[nu * 8 + head]));
    uint2 q = h1u2[(size_t)nu * 64 + lane];
    float f0, f1, f2, f3; unpack2(q.x, f0, f1); unpack2(q.y, f2, f3);
    z = w0; a0 = w0 * f0; a1 = w0 * f1; a2 = w0 * f2; a3 = w0 * f3;
  }
  for (int base = start; base < end; base += 32) {
    const int cnt = min(32, end - base);
    // ---- weight phase: lanes 0-31 heads 0-3, lanes 32-63 heads 4-7 ----
    int s = 0;
    if (hl < cnt) s = esrc[base + hl];
    const int hb4 = half << 2;           // 0 or 4
    const float4 av = *(const float4*)(as1 + (size_t)s * 8 + hb4);
    float w0 = __expf(lrelu(av.x + dn4.x));
    float w1 = __expf(lrelu(av.y + dn4.y));
    float w2 = __expf(lrelu(av.z + dn4.z));
    float w3 = __expf(lrelu(av.w + dn4.w));
    const bool act = hl < cnt;
    wl[w][hb4 + 0][hl] = act ? w0 : 0.f;
    wl[w][hb4 + 1][hl] = act ? w1 : 0.f;
    wl[w][hb4 + 2][hl] = act ? w2 : 0.f;
    wl[w][hb4 + 3][hl] = act ? w3 : 0.f;
    // same-wave LDS write->read: compiler inserts lgkmcnt wait
    const int cnt4 = (cnt + 3) & ~3;
    int jb = 0;
    for (; jb + 8 <= cnt4; jb += 8) {
      uint2 q[8];
#pragma unroll
      for (int u = 0; u < 8; ++u) {
        const int sj = esrc[base + jb + u];            // uniform -> s_load
        q[u] = h1u2[(size_t)sj * 64 + lane];
      }
      const float4 wq0 = *(const float4*)&wl[w][head][jb];
      const float4 wq1 = *(const float4*)&wl[w][head][jb + 4];
      z += ((wq0.x + wq0.y) + (wq0.z + wq0.w)) + ((wq1.x + wq1.y) + (wq1.z + wq1.w));
      float f0, f1, f2, f3;
      unpack2(q[0].x, f0, f1); unpack2(q[0].y, f2, f3);
      a0 += wq0.x * f0; a1 += wq0.x * f1; a2 += wq0.x * f2; a3 += wq0.x * f3;
      unpack2(q[1].x, f0, f1); unpack2(q[1].y, f2, f3);
      a0 += wq0.y * f0; a1 += wq0.y * f1; a2 += wq0.y * f2; a3 += wq0.y * f3;
      unpack2(q[2].x, f0, f1); unpack2(q[2].y, f2, f3);
      a0 += wq0.z * f0; a1 += wq0.z * f1; a2 += wq0.z * f2; a3 += wq0.z * f3;
      unpack2(q[3].x, f0, f1); unpack2(q[3].y, f2, f3);
      a0 += wq0.w * f0; a1 += wq0.w * f1; a2 += wq0.w * f2; a3 += wq0.w * f3;
      unpack2(q[4].x, f0, f1); unpack2(q[4].y, f2, f3);
      a0 += wq1.x * f0; a1 += wq1.x * f1; a2 += wq1.x * f2; a3 += wq1.x * f3;
      unpack2(q[5].x, f0, f1); unpack2(q[5].y, f2, f3);
      a0 += wq1.y * f0; a1 += wq1.y * f1; a2 += wq1.y * f2; a3 += wq1.y * f3;
      unpack2(q[6].x, f0, f1); unpack2(q[6].y, f2, f3);
      a0 += wq1.z * f0; a1 += wq1.z * f1; a2 += wq1.z * f2; a3 += wq1.z * f3;
      unpack2(q[7].x, f0, f1); unpack2(q[7].y, f2, f3);
      a0 += wq1.w * f0; a1 += wq1.w * f1; a2 += wq1.w * f2; a3 += wq1.w * f3;
    }
    if (jb < cnt4) {   // 4-edge tail batch
      uint2 q[4];
#pragma unroll
      for (int u = 0; u < 4; ++u) {
        const int sj = esrc[base + jb + u];            // uniform -> s_load
        q[u] = h1u2[(size_t)sj * 64 + lane];
      }
      const float4 wq0 = *(const float4*)&wl[w][head][jb];
      z += (wq0.x + wq0.y) + (wq0.z + wq0.w);
      float f0, f1, f2, f3;
      unpack2(q[0].x, f0, f1); unpack2(q[0].y, f2, f3);
      a0 += wq0.x * f0; a1 += wq0.x * f1; a2 += wq0.x * f2; a3 += wq0.x * f3;
      unpack2(q[1].x, f0, f1); unpack2(q[1].y, f2, f3);
      a0 += wq0.y * f0; a1 += wq0.y * f1; a2 += wq0.y * f2; a3 += wq0.y * f3;
      unpack2(q[2].x, f0, f1); unpack2(q[2].y, f2, f3);
      a0 += wq0.z * f0; a1 += wq0.z * f1; a2 += wq0.z * f2; a3 += wq0.z * f3;
      unpack2(q[3].x, f0, f1); unpack2(q[3].y, f2, f3);
      a0 += wq0.w * f0; a1 += wq0.w * f1; a2 += wq0.w * f2; a3 += wq0.w * f3;
    }
  }
  // out1 = acc/z + b1, ELU; bf16 hi/lo split to LDS (channels 4*lane..+3)
  {
    const float zi = 1.0f / (z + 1e-16f);
    const float4 bb = *(const float4*)(b1 + 4 * lane);
    float v0 = a0 * zi + bb.x;
    float v1 = a1 * zi + bb.y;
    float v2 = a2 * zi + bb.z;
    float v3 = a3 * zi + bb.w;
    v0 = v0 > 0.f ? v0 : (__expf(v0) - 1.0f);
    v1 = v1 > 0.f ? v1 : (__expf(v1) - 1.0f);
    v2 = v2 > 0.f ? v2 : (__expf(v2) - 1.0f);
    v3 = v3 > 0.f ? v3 : (__expf(v3) - 1.0f);
    ushort4 hh, ll;
    hh.x = f2bf(v0); hh.y = f2bf(v1); hh.z = f2bf(v2); hh.w = f2bf(v3);
    ll.x = f2bf(v0 - bf2f(hh.x));
    ll.y = f2bf(v1 - bf2f(hh.y));
    ll.z = f2bf(v2 - bf2f(hh.z));
    ll.w = f2bf(v3 - bf2f(hh.w));
    *(ushort4*)&o1hi[w][4 * lane] = hh;
    *(ushort4*)&o1lo[w][4 * lane] = ll;
  }
  __syncthreads();
  if (w == 0) {
    // GEMM2: M=8 nodes x N=32 x K=256 on the matrix pipe (hi/lo split ~ f32)
    const int ml = lane & 15;
    const int quad = lane >> 4;
    const int mr = ml & 7;               // rows 8..15 duplicate rows 0..7 (ignored)
    v4f acc[2];
    acc[0] = (v4f){0.f, 0.f, 0.f, 0.f};
    acc[1] = (v4f){0.f, 0.f, 0.f, 0.f};
#pragma unroll
    for (int kk = 0; kk < 8; ++kk) {
      const int k0 = kk * 32 + quad * 8;
      v8s ah = *(const v8s*)&o1hi[mr][k0];
      v8s al = *(const v8s*)&o1lo[mr][k0];
#pragma unroll
      for (int tt = 0; tt < 2; ++tt) {
        v8s bh = *(const v8s*)(W2thi + (size_t)(tt * 16 + ml) * 256 + k0);
        v8s bl = *(const v8s*)(W2tlo + (size_t)(tt * 16 + ml) * 256 + k0);
        acc[tt] = __builtin_amdgcn_mfma_f32_16x16x32_bf16(ah, bh, acc[tt], 0, 0, 0);
        acc[tt] = __builtin_amdgcn_mfma_f32_16x16x32_bf16(al, bh, acc[tt], 0, 0, 0);
        acc[tt] = __builtin_amdgcn_mfma_f32_16x16x32_bf16(ah, bl, acc[tt], 0, 0, 0);
      }
    }
    // valid C rows 0..7 = quad 0 (r=0..3) and quad 1 (r=4..7)
    if (quad < 2) {
      const float s0 = att_src2[ml], s1 = att_src2[16 + ml];
      const float d0 = att_dst2[ml], d1 = att_dst2[16 + ml];
#pragma unroll
      for (int r = 0; r < 4; ++r) {
        const int nn = n0 + quad * 4 + r;
        const float h0 = acc[0][r], h1v = acc[1][r];
        h2b[(size_t)nn * 32 + ml] = f2bf(h0);
        h2b[(size_t)nn * 32 + 16 + ml] = f2bf(h1v);
        float ps = h0 * s0 + h1v * s1;
        float pd = h0 * d0 + h1v * d1;
        ps += __shfl_xor(ps, 1, 64); ps += __shfl_xor(ps, 2, 64);
        ps += __shfl_xor(ps, 4, 64); ps += __shfl_xor(ps, 8, 64);
        pd += __shfl_xor(pd, 1, 64); pd += __shfl_xor(pd, 2, 64);
        pd += __shfl_xor(pd, 4, 64); pd += __shfl_xor(pd, 8, 64);
        if (ml == 0) { as2[nn] = ps; ad2[nn] = pd; }
      }
    }
  }
}

// ---------------- agg2: wave-per-node, LDS (src,weight) chunk, 8 edges in flight ---
// R8-verified. Slot group handles edges 8j+slot and 8j+4+slot; OOB swl = (0,0.0).
__global__ __launch_bounds__(256) void k_agg2(const unsigned short* __restrict__ h2b,
                                              const float* __restrict__ as2,
                                              const float* __restrict__ ad2,
                                              const int* __restrict__ offs,
                                              const int* __restrict__ esrc,
                                              const float* __restrict__ b2,
                                              float* __restrict__ h3) {
  __shared__ int2 swl[4][64];   // per-wave (src, weight-bits)
  const int t = threadIdx.x;
  const int lane = t & 63;
  const int wv = t >> 6;
  const int n = __builtin_amdgcn_readfirstlane(blockIdx.x * 4 + wv);  // NN = 25000*4
  const int col = lane & 15;
  const int slot = lane >> 4;
  const unsigned int* __restrict__ h2u = (const unsigned int*)h2b;
  const int start = offs[n], end = offs[n + 1];   // s_load
  const float adn = ad2[n];                       // s_load
  float z = 0.f, acc0 = 0.f, acc1 = 0.f;
  if (slot == 0) {   // self loop counted once
    float w0 = __expf(lrelu(as2[n] + adn));
    unsigned int q = h2u[(unsigned)(n * 16 + col)];
    float f0, f1; unpack2(q, f0, f1);
    z = w0; acc0 = w0 * f0; acc1 = w0 * f1;
  }
  for (int base = start; base < end; base += 64) {
    const int cnt = min(64, end - base);
    int s = 0; float wgt = 0.f;
    if (lane < cnt) {
      s = esrc[base + lane];
      wgt = __expf(lrelu(as2[s] + adn));
    }
    swl[wv][lane] = make_int2(s, __float_as_int(wgt));
    // same-wave LDS write->read: compiler inserts lgkmcnt wait
    const int nit = (cnt + 7) >> 3;
#pragma unroll 2
    for (int j = 0; j < nit; ++j) {
      const int2 p0 = swl[wv][8 * j + slot];
      const int2 p1 = swl[wv][8 * j + 4 + slot];
      const unsigned int q0 = h2u[(unsigned)(p0.x * 16 + col)];
      const unsigned int q1 = h2u[(unsigned)(p1.x * 16 + col)];
      const float wj0 = __int_as_float(p0.y);
      const float wj1 = __int_as_float(p1.y);
      float f0, f1, g0, g1;
      unpack2(q0, f0, f1); unpack2(q1, g0, g1);
      z += wj0 + wj1;
      acc0 += wj0 * f0; acc0 += wj1 * g0;
      acc1 += wj0 * f1; acc1 += wj1 * g1;
    }
  }
  // combine the 4 slot groups
  acc0 += __shfl_xor(acc0, 16, 64); acc0 += __shfl_xor(acc0, 32, 64);
  acc1 += __shfl_xor(acc1, 16, 64); acc1 += __shfl_xor(acc1, 32, 64);
  z    += __shfl_xor(z, 16, 64);    z    += __shfl_xor(z, 32, 64);
  if (slot == 0) {
    const float zi = 1.0f / (z + 1e-16f);
    float2 bb = *(const float2*)(b2 + 2 * col);
    float2 o;
    o.x = acc0 * zi + bb.x;
    o.y = acc1 * zi + bb.y;
    *(float2*)(h3 + (size_t)n * 32 + 2 * col) = o;
  }
}

// ---------------- pool + final linear (fused) ----------------
__global__ __launch_bounds__(256) void k_poolfin(const float* __restrict__ h3,
                                                 const int* __restrict__ batch,
                                                 const float* __restrict__ Wlin,
                                                 const float* __restrict__ blin,
                                                 float* __restrict__ out) {
  __shared__ int bounds[2];
  __shared__ float red[8][33];
  __shared__ float mean[32];
  const int g = blockIdx.x;
  const int t = threadIdx.x;
  if (t < 2) {
    int target = g + t;
    int lo = 0, hi = NN;
    while (lo < hi) { int mid = (lo + hi) >> 1; if (batch[mid] < target) lo = mid + 1; else hi = mid; }
    bounds[t] = lo;
  }
  __syncthreads();
  const int lo = bounds[0], hi = bounds[1];
  const int rr = t >> 5, c = t & 31;
  float a = 0.f;
  for (int r = lo + rr; r < hi; r += 8) a += h3[(size_t)r * 32 + c];
  red[rr][c] = a;
  __syncthreads();
  if (rr == 0) {
    float s = 0.f;
#pragma unroll
    for (int i = 0; i < 8; ++i) s += red[i][c];
    float ct = (float)(hi - lo);
    ct = ct > 1.f ? ct : 1.f;
    mean[c] = s / ct;
  }
  __syncthreads();
  if (t < NC) {
    float acc = 0.f;
#pragma unroll
    for (int cc = 0; cc < 32; ++cc) acc += mean[cc] * Wlin[cc * NC + t];
    out[g * NC + t] = acc + blin[t];
  }
}

extern "C" void kernel_launch(void* const* d_in, const int* in_sizes, int n_in,
                              void* d_out, int out_size, void* d_ws, size_t ws_size,
                              hipStream_t stream) {
  const float* x        = (const float*)d_in[0];
  const int*   ei       = (const int*)d_in[1];
  const int*   batch    = (const int*)d_in[2];
  const float* W1       = (const float*)d_in[3];
  const float* att_src1 = (const float*)d_in[4];
  const float* att_dst1 = (const float*)d_in[5];
  const float* b1       = (const float*)d_in[6];
  const float* W2       = (const float*)d_in[7];
  const float* att_src2 = (const float*)d_in[8];
  const float* att_dst2 = (const float*)d_in[9];
  const float* b2       = (const float*)d_in[10];
  const float* Wlin     = (const float*)d_in[11];
  const float* blin     = (const float*)d_in[12];
  float* out = (float*)d_out;
  char* ws = (char*)d_ws;

  // workspace layout (bytes); peak ~85.3 MB (xb eliminated)
  unsigned short* h1b   = (unsigned short*)(ws + 0);         // 51,200,000
  float* as1    = (float*)(ws + 51200000);                   // 3,200,000
  float* ad1    = (float*)(ws + 54400000);                   // 3,200,000
  int* counts   = (int*)(ws + 57600000);                     // 400,000
  int* offs     = (int*)(ws + 58000000);                     // 400,004 (+pad)
  int* cursor   = (int*)(ws + 58400256);                     // 400,000
  int* esrc     = (int*)(ws + 58800256);                     // 6,400,000 + 64B zero pad
  int* bsums    = (int*)(ws + 65200384);                     // 1,564 (+pad)
  unsigned short* h2b   = (unsigned short*)(ws + 65202048);  // 6,400,000
  float* as2    = (float*)(ws + 71602048);                   // 400,000
  float* ad2    = (float*)(ws + 72002048);                   // 400,000
  unsigned short* W1tg  = (unsigned short*)(ws + 72402048);  // 65,536
  unsigned short* W2thi = (unsigned short*)(ws + 72467584);  // 16,384
  unsigned short* W2tlo = (unsigned short*)(ws + 72483968);  // 16,384
  float* h3     = (float*)(ws + 72500352);                   // 12,800,000

  const int nb_scan = (NN + 255) / 256;  // 391

  hipMemsetAsync(counts, 0, NN * sizeof(int), stream);
  k_prep<<<6538, 256, 0, stream>>>(ei, counts, W1, W1tg, W2, W2thi, W2tlo);

  dim3 g1((NN + 63) / 64, 2);
  k_gemm1<<<g1, 256, 0, stream>>>(x, W1tg, att_src1, att_dst1, h1b, as1, ad1);

  k_scan1<<<nb_scan, 256, 0, stream>>>(counts, offs, bsums);
  k_scan2<<<1, 512, 0, stream>>>(bsums, nb_scan);
  k_scan3<<<nb_scan, 256, 0, stream>>>(offs, bsums, cursor, esrc);
  k_scatter<<<(EE + 255) / 256, 256, 0, stream>>>(ei, cursor, esrc);

  k_agg1<<<NN / 8, 512, 0, stream>>>(h1b, as1, ad1, offs, esrc, b1, W2thi, W2tlo,
                                     att_src2, att_dst2, h2b, as2, ad2);

  k_agg2<<<NN / 4, 256, 0, stream>>>(h2b, as2, ad2, offs, esrc, b2, h3);
  k_poolfin<<<GG, 256, 0, stream>>>(h3, batch, Wlin, blin, out);
}